// Round 9
// baseline (510.127 us; speedup 1.0000x reference)
//
#include <hip/hip_runtime.h>
#include <cstddef>
#include <cstdint>

// ---------------------------------------------------------------------------
// Swin block. f32 in/out; internal bf16 MFMA. B=8 H=W=64 DIM=512 NH=16 HD=32.
// GEMM: 128x128 tile, BK=64, 2-barrier loop, LINEAR LDS [128][64] staged via
// __builtin_amdgcn_global_load_lds width=16 (m97 structure) — VERIFIED R4
// (818 TF QKV). R8's 256x128 counted-vmcnt ring LOST to this (645 TF): a
// coarse phase-split without the fine 8-phase interleave hurts (m196), and
// 1 block/CU sacrificed the 4-block implicit overlap (m114). Keep this.
// Bank-conflict fix (rule #21): LDS dest linear, global SOURCE chunk XOR-
// swizzled (c ^= row&7), same XOR on ds_read side -> conflicts = 0.
// launch_bounds(256,4): VGPR=60. (256,5) strangles VGPR->48 (R2: 803us).
// T1: bijective XCD swizzle (verified R4: QKV FETCH 135->28MB).
// M_GELU: branch-free A&S erf (verified R3).
// MLP N-SPLIT (this round): split fc1-N/fc2-K into 2x1024 instead of M into
// halves. gbuf = 32768x1024 bf16 = 64MB (exact fit over k+v). FINAL then has
// M=32768 -> grid (4,256)=1024 blocks = 4 blocks/CU (was 512 = 2/CU, the
// measured 555-vs-818 TF deficit). FINAL is RMW; bias added on slice 0 only.
// ws: [0,6.3M) bf16 weights | q[8,40) k[40,72) v[72,104) MB
//     h2 overlays q after proj; gbuf (32768x1024 bf16) overlays k+v.
// xw (LN1+shift, bf16 32MB) lives in d_out (dead until proj overwrites it).
// ---------------------------------------------------------------------------

typedef unsigned short u16;
typedef __attribute__((ext_vector_type(8))) short short8;
typedef __attribute__((ext_vector_type(4))) float floatx4;

__device__ __forceinline__ float bf2f(u16 u) {
    union { float f; unsigned i; } w; w.i = ((unsigned)u) << 16; return w.f;
}
__device__ __forceinline__ u16 f2bf(float f) {
    union { float f; unsigned i; } w; w.f = f;
    unsigned r = w.i + 0x7FFF + ((w.i >> 16) & 1);   // RNE
    return (u16)(r >> 16);
}

__device__ __forceinline__ void gload_lds16(const u16* g, u16* l) {
    __builtin_amdgcn_global_load_lds(
        (const __attribute__((address_space(1))) void*)g,
        (__attribute__((address_space(3))) void*)l, 16, 0, 0);
}

// branch-free erf, A&S 7.1.26, |err| < 1.5e-7 (invisible at bf16 precision)
__device__ __forceinline__ float erf_fast(float x) {
    float ax = fabsf(x);
    float t = 1.0f / (1.0f + 0.3275911f * ax);
    float poly = ((((1.061405429f * t - 1.453152027f) * t + 1.421413741f) * t
                   - 0.284496736f) * t + 0.254829592f) * t;
    float er = 1.0f - poly * __expf(-ax * ax);
    return copysignf(er, x);
}

__device__ __forceinline__ int win_to_img_row(int t) {
    int win = t >> 6, n = t & 63;
    int b = win >> 6, wr = (win >> 3) & 7, wc = win & 7;
    int h = ((wr << 3) + (n >> 3) + 4) & 63;
    int w = ((wc << 3) + (n & 7) + 4) & 63;
    return (b << 12) + (h << 6) + w;
}

// ---------------------------------------------------------------------------
// Fused LayerNorm: one wave per 512-dim row, single pass.
// ---------------------------------------------------------------------------
__global__ __launch_bounds__(256) void ln_fused(
    const float* __restrict__ x, const float* __restrict__ g,
    const float* __restrict__ b, u16* __restrict__ out, int gather)
{
    int wave = threadIdx.x >> 6, lane = threadIdx.x & 63;
    int t = blockIdx.x * 4 + wave;
    int src = gather ? win_to_img_row(t) : t;
    const float* xr = x + (size_t)src * 512 + lane * 8;
    float4 a = *(const float4*)xr;
    float4 c = *(const float4*)(xr + 4);
    float s = a.x + a.y + a.z + a.w + c.x + c.y + c.z + c.w;
    float s2 = a.x*a.x + a.y*a.y + a.z*a.z + a.w*a.w
             + c.x*c.x + c.y*c.y + c.z*c.z + c.w*c.w;
#pragma unroll
    for (int off = 32; off; off >>= 1) { s += __shfl_down(s, off); s2 += __shfl_down(s2, off); }
    s = __shfl(s, 0); s2 = __shfl(s2, 0);
    float mu = s * (1.f / 512.f);
    float var = s2 * (1.f / 512.f) - mu * mu;
    float rs = rsqrtf(var + 1e-5f);
    int col = lane * 8;
    float4 g0 = *(const float4*)(g + col), g1 = *(const float4*)(g + col + 4);
    float4 b0 = *(const float4*)(b + col), b1 = *(const float4*)(b + col + 4);
    u16 r[8];
    r[0] = f2bf((a.x - mu) * rs * g0.x + b0.x);
    r[1] = f2bf((a.y - mu) * rs * g0.y + b0.y);
    r[2] = f2bf((a.z - mu) * rs * g0.z + b0.z);
    r[3] = f2bf((a.w - mu) * rs * g0.w + b0.w);
    r[4] = f2bf((c.x - mu) * rs * g1.x + b1.x);
    r[5] = f2bf((c.y - mu) * rs * g1.y + b1.y);
    r[6] = f2bf((c.z - mu) * rs * g1.z + b1.z);
    r[7] = f2bf((c.w - mu) * rs * g1.w + b1.w);
    *(uint4*)(out + (size_t)t * 512 + col) = *(const uint4*)r;
}

// ---------------------------------------------------------------------------
// All four weight transposes in ONE launch (saves 3 launch overheads).
// Block ranges: [0,384) qkv 512x1536 | [384,512) proj 512x512 |
// [512,1024) fc1 512x2048 | [1024,1536) fc2 2048x512.
// ---------------------------------------------------------------------------
__global__ __launch_bounds__(256) void transpose_all(
    const float* __restrict__ qkv_w, const float* __restrict__ proj_w,
    const float* __restrict__ fc1_w, const float* __restrict__ fc2_w,
    u16* __restrict__ qkvT, u16* __restrict__ projT,
    u16* __restrict__ fc1T, u16* __restrict__ fc2T)
{
    int bid = blockIdx.x;
    const float* W; u16* WT; int K, N, base;
    if (bid < 384)       { W = qkv_w;  WT = qkvT;  K = 512;  N = 1536; base = 0; }
    else if (bid < 512)  { W = proj_w; WT = projT; K = 512;  N = 512;  base = 384; }
    else if (bid < 1024) { W = fc1_w;  WT = fc1T;  K = 512;  N = 2048; base = 512; }
    else                 { W = fc2_w;  WT = fc2T;  K = 2048; N = 512;  base = 1024; }
    int f = (bid - base) * 256 + threadIdx.x;
    int n = f % N, kc = f / N;
    if (kc >= (K >> 3)) return;
    int k0 = kc << 3;
    u16 r[8];
#pragma unroll
    for (int j = 0; j < 8; ++j) r[j] = f2bf(W[(size_t)(k0 + j) * N + n]);
    *(uint4*)(WT + (size_t)n * K + k0) = *(const uint4*)r;
}

// ---------------------------------------------------------------------------
// MFMA GEMM: 128x128 tile, BK=64, linear LDS [128][64] u16 (16 KiB each),
// staged with global_load_lds width=16. Staging index f = l*256+tid:
// row = f>>3, chunk c = f&7; LDS dest byte = f*16 (lane-linear). Source chunk
// swizzle cs = c ^ (row&7); fragment ds_read applies the same XOR.
// Grid: T1 bijective XCD swizzle. ASRC: 0 plain A[lda] | 3 qkv-slice gather.
// ldo: output row stride for M_GELU. M_FINAL: bias may be nullptr (K-split).
// ---------------------------------------------------------------------------
enum { M_QKV = 0, M_PROJ = 1, M_GELU = 2, M_FINAL = 3 };

template <int MODE, int ASRC>
__global__ __launch_bounds__(256, 4) void gemm_bt(
    const u16* __restrict__ A, int lda,
    const u16* __restrict__ BT, int ldb,
    const float* __restrict__ bias,
    void* __restrict__ outp, const float* __restrict__ auxf, int K, int ldo)
{
    __shared__ __align__(16) u16 As[128 * 64];
    __shared__ __align__(16) u16 Bs[128 * 64];

    int tid = threadIdx.x;
    // ---- T1: bijective XCD-aware block swizzle (8 XCDs) ----
    int nwg = gridDim.x * gridDim.y;
    int bid = blockIdx.y * gridDim.x + blockIdx.x;
    int q8 = nwg >> 3, r8 = nwg & 7;
    int xcd = bid & 7, pos = bid >> 3;
    int swz = (xcd < r8 ? xcd * (q8 + 1)
                        : r8 * (q8 + 1) + (xcd - r8) * q8) + pos;
    int bx = swz % gridDim.x, by = swz / gridDim.x;
    int bm = by * 128, bn = bx * 128;

    int wave = tid >> 6, lane = tid & 63;
    int quad = lane >> 4, lr = lane & 15;
    int wm = (wave >> 1) * 64, wn = (wave & 1) * 64;

    floatx4 acc[4][4] = {};

    for (int k0 = 0; k0 < K; k0 += 64) {
#pragma unroll
        for (int l = 0; l < 4; ++l) {
            int f = (l << 8) + tid;            // 0..1023
            int row = f >> 3, c = f & 7;
            int cs = c ^ (row & 7);            // source-side XOR swizzle
            int kk = k0 + (cs << 3);
            const u16* gb = BT + (size_t)(bn + row) * ldb + kk;
            gload_lds16(gb, Bs + f * 8);
            if constexpr (ASRC == 0) {
                gload_lds16(A + (size_t)(bm + row) * lda + kk, As + f * 8);
            } else {  // qkv-slice gather: [ (win*16+head)*2048 + tok*32 + d ]
                int m = bm + row;
                gload_lds16(A + (size_t)(((m >> 6) << 4) + (kk >> 5)) * 2048
                              + (m & 63) * 32 + (kk & 31), As + f * 8);
            }
        }
        __syncthreads();   // drains vmcnt(0): loads have landed in LDS
#pragma unroll
        for (int step = 0; step < 2; ++step) {
            short8 af[4], bv[4];
            int kc = step * 4 + quad;
#pragma unroll
            for (int t = 0; t < 4; ++t) {
                int ra = wm + t * 16 + lr;
                int rb = wn + t * 16 + lr;
                af[t] = *(const short8*)(As + ra * 64 + ((kc ^ (ra & 7)) << 3));
                bv[t] = *(const short8*)(Bs + rb * 64 + ((kc ^ (rb & 7)) << 3));
            }
#pragma unroll
            for (int mt = 0; mt < 4; ++mt)
#pragma unroll
                for (int nt = 0; nt < 4; ++nt)
                    acc[mt][nt] = __builtin_amdgcn_mfma_f32_16x16x32_bf16(
                        af[mt], bv[nt], acc[mt][nt], 0, 0, 0);
        }
        __syncthreads();
    }

#pragma unroll
    for (int mt = 0; mt < 4; ++mt) {
#pragma unroll
        for (int nt = 0; nt < 4; ++nt) {
            int m0 = bm + wm + mt * 16 + quad * 4;
            int n = bn + wn + nt * 16 + lr;
#pragma unroll
            for (int i = 0; i < 4; ++i) {
                int m = m0 + i;
                float v = acc[mt][nt][i];
                if constexpr (MODE == M_QKV) {
                    v += bias[n];
                    int sel = n >> 9, head = (n >> 5) & 15, d = n & 31;
                    int wh = (m >> 6) * 16 + head, tok = m & 63;
                    ((u16*)outp)[(size_t)sel * 16777216 + (size_t)wh * 2048 + tok * 32 + d] = f2bf(v);
                } else if constexpr (MODE == M_PROJ) {
                    size_t idx = (size_t)win_to_img_row(m) * 512 + n;
                    ((float*)outp)[idx] = v + bias[n] + auxf[idx];
                } else if constexpr (MODE == M_GELU) {
                    v += bias[n];
                    float gel = 0.5f * v * (1.0f + erf_fast(v * 0.70710678118654752f));
                    ((u16*)outp)[(size_t)m * ldo + n] = f2bf(gel);
                } else { // M_FINAL: outp = xres f32, read-modify-write.
                    // bias==nullptr on K-split slices > 0.
                    size_t idx = (size_t)m * 512 + n;
                    float* o = (float*)outp;
                    float bb = bias ? bias[n] : 0.0f;
                    o[idx] = o[idx] + v + bb;
                }
            }
        }
    }
}

// ---------------------------------------------------------------------------
// MFMA attention (unchanged): block = 4 waves = 4 windows x 1 head.
// No T1 here: each block reads private q/k/v rows (zero inter-block reuse).
// ---------------------------------------------------------------------------
__global__ __launch_bounds__(256) void attn_mfma(
    const u16* __restrict__ qkv, const float* __restrict__ table,
    u16* __restrict__ outp)
{
    __shared__ __align__(8) u16 PT[4][64 * 76];
    __shared__ float blds[225];

    int w = threadIdx.x >> 6, lane = threadIdx.x & 63;
    int head = blockIdx.x & 15, win = ((blockIdx.x >> 4) << 2) + w;
    int wh = (win << 4) + head;
    int quad = lane >> 4, lr = lane & 15;
    const u16* qb = qkv + (size_t)wh * 2048;
    const u16* kb = qb + 16777216;
    const u16* vb = qb + 33554432;
    u16* PTw = PT[w];

    for (int i = threadIdx.x; i < 225; i += 256) blds[i] = table[i * 16 + head];
    __syncthreads();

    short8 qf[4], kf[4];
#pragma unroll
    for (int t = 0; t < 4; ++t) {
        qf[t] = *(const short8*)(qb + (t * 16 + lr) * 32 + quad * 8);
        kf[t] = *(const short8*)(kb + (t * 16 + lr) * 32 + quad * 8);
    }
    floatx4 s[4][4] = {};
#pragma unroll
    for (int mi = 0; mi < 4; ++mi)
#pragma unroll
        for (int ni = 0; ni < 4; ++ni)
            s[mi][ni] = __builtin_amdgcn_mfma_f32_16x16x32_bf16(qf[mi], kf[ni], s[mi][ni], 0, 0, 0);

    short8 vf[2][2];
#pragma unroll
    for (int ks = 0; ks < 2; ++ks)
#pragma unroll
        for (int nd = 0; nd < 2; ++nd)
#pragma unroll
            for (int j = 0; j < 8; ++j)
                vf[ks][nd][j] = (short)vb[(ks * 32 + quad * 8 + j) * 32 + nd * 16 + lr];

    int wr = (win >> 3) & 7, wc = win & 7;
    int rj[4], cj[4], regj[4];
#pragma unroll
    for (int ni = 0; ni < 4; ++ni) {
        int kj = ni * 16 + lr;
        rj[ni] = kj >> 3; cj[ni] = kj & 7;
        int hJ = wr * 8 + rj[ni], wJ = wc * 8 + cj[ni];
        regj[ni] = (hJ < 56 ? 0 : (hJ < 60 ? 1 : 2)) * 3 + (wJ < 56 ? 0 : (wJ < 60 ? 1 : 2));
    }
    float rm[4][4], linv[4][4];
#pragma unroll
    for (int mi = 0; mi < 4; ++mi) {
#pragma unroll
        for (int i = 0; i < 4; ++i) {
            int qi = mi * 16 + quad * 4 + i;
            int ri = qi >> 3, ci = qi & 7;
            int hI = wr * 8 + ri, wI = wc * 8 + ci;
            int regi = (hI < 56 ? 0 : (hI < 60 ? 1 : 2)) * 3 + (wI < 56 ? 0 : (wI < 60 ? 1 : 2));
            float mx = -1e30f;
#pragma unroll
            for (int ni = 0; ni < 4; ++ni) {
                float v = s[mi][ni][i] * 0.17677669529663687f
                        + blds[(ri - rj[ni] + 7) * 15 + (ci - cj[ni] + 7)];
                if (regj[ni] != regi) v -= 100.f;
                s[mi][ni][i] = v;
                mx = fmaxf(mx, v);
            }
            rm[mi][i] = mx;
        }
    }
#pragma unroll
    for (int mi = 0; mi < 4; ++mi)
#pragma unroll
        for (int i = 0; i < 4; ++i) {
            float mx = rm[mi][i];
#pragma unroll
            for (int msk = 1; msk < 16; msk <<= 1) mx = fmaxf(mx, __shfl_xor(mx, msk));
            float sum = 0.f;
#pragma unroll
            for (int ni = 0; ni < 4; ++ni) {
                float e = __expf(s[mi][ni][i] - mx);
                s[mi][ni][i] = e;
                sum += e;
            }
#pragma unroll
            for (int msk = 1; msk < 16; msk <<= 1) sum += __shfl_xor(sum, msk);
            linv[mi][i] = 1.f / sum;
        }

#pragma unroll
    for (int mi = 0; mi < 4; ++mi)
#pragma unroll
        for (int ni = 0; ni < 4; ++ni) {
            unsigned lo = (unsigned)f2bf(s[mi][ni][0]) | ((unsigned)f2bf(s[mi][ni][1]) << 16);
            unsigned hi = (unsigned)f2bf(s[mi][ni][2]) | ((unsigned)f2bf(s[mi][ni][3]) << 16);
            uint2 pk = make_uint2(lo, hi);
            *(uint2*)(PTw + (ni * 16 + lr) * 76 + mi * 16 + quad * 4) = pk;
        }
    __syncthreads();

    floatx4 o[4][2] = {};
#pragma unroll
    for (int mi = 0; mi < 4; ++mi) {
#pragma unroll
        for (int ks = 0; ks < 2; ++ks) {
            short8 pa;
#pragma unroll
            for (int j = 0; j < 8; ++j)
                pa[j] = (short)PTw[(ks * 32 + quad * 8 + j) * 76 + mi * 16 + lr];
#pragma unroll
            for (int nd = 0; nd < 2; ++nd)
                o[mi][nd] = __builtin_amdgcn_mfma_f32_16x16x32_bf16(pa, vf[ks][nd], o[mi][nd], 0, 0, 0);
        }
    }
    u16* ob = outp + (size_t)wh * 2048;
#pragma unroll
    for (int mi = 0; mi < 4; ++mi)
#pragma unroll
        for (int nd = 0; nd < 2; ++nd)
#pragma unroll
            for (int i = 0; i < 4; ++i) {
                int qi = mi * 16 + quad * 4 + i;
                ob[qi * 32 + nd * 16 + lr] = f2bf(o[mi][nd][i] * linv[mi][i]);
            }
}

// ---------------------------------------------------------------------------
extern "C" void kernel_launch(void* const* d_in, const int* in_sizes, int n_in,
                              void* d_out, int out_size, void* d_ws, size_t ws_size,
                              hipStream_t stream)
{
    (void)in_sizes; (void)n_in; (void)out_size; (void)ws_size;
    const float* x      = (const float*)d_in[0];
    const float* n1g    = (const float*)d_in[2];
    const float* n1b    = (const float*)d_in[3];
    const float* qkv_w  = (const float*)d_in[4];
    const float* qkv_b  = (const float*)d_in[5];
    const float* table  = (const float*)d_in[6];
    const float* proj_w = (const float*)d_in[7];
    const float* proj_b = (const float*)d_in[8];
    const float* n2g    = (const float*)d_in[9];
    const float* n2b    = (const float*)d_in[10];
    const float* fc1_w  = (const float*)d_in[11];
    const float* fc1_b  = (const float*)d_in[12];
    const float* fc2_w  = (const float*)d_in[13];
    const float* fc2_b  = (const float*)d_in[14];
    float* out = (float*)d_out;
    char* ws = (char*)d_ws;

    u16* qkvT  = (u16*)ws;                  // 786432
    u16* projT = qkvT + 786432;             // 262144
    u16* fc1T  = projT + 262144;            // 1048576
    u16* fc2T  = fc1T + 1048576;            // 1048576 (ends 6,291,456 B)
    u16* q    = (u16*)(ws + 8388608);       // q,k,v 3x32MB (ends 104 MB)
    u16* h2   = q;                          // overlays q after proj
    u16* gbuf = q + 16777216;               // 64 MB over k+v (dead post-attn)
    u16* xw   = (u16*)d_out;                // LN1+shift bf16, dead before proj

    transpose_all<<<1536, 256, 0, stream>>>(
        qkv_w, proj_w, fc1_w, fc2_w, qkvT, projT, fc1T, fc2T);

    // LN1 + shift/window gather -> xw (in d_out)
    ln_fused<<<8192, 256, 0, stream>>>(x, n1g, n1b, xw, 1);
    // QKV from xw (M=32768, N=1536, K=512)
    gemm_bt<M_QKV, 0><<<dim3(12, 256), 256, 0, stream>>>(
        xw, 512, qkvT, 512, qkv_b, q, nullptr, 512, 0);
    attn_mfma<<<2048, 256, 0, stream>>>(q, table, q);
    // proj + reverse-shift scatter + residual -> d_out (overwrites xw fully)
    gemm_bt<M_PROJ, 3><<<dim3(4, 256), 256, 0, stream>>>(
        q, 0, projT, 512, proj_b, out, x, 512, 0);
    // LN2 -> h2 (full 32768 rows)
    ln_fused<<<8192, 256, 0, stream>>>(out, n2g, n2b, h2, 0);
    // MLP, N-split: for each 1024-wide slice of the hidden dim:
    //   GELU: h2 @ fc1[:, nc] -> gbuf (32768x1024, exact 64MB fit)
    //   FINAL: out += gbuf @ fc2[nc, :]  (K=1024, grid 1024 blocks = 4/CU)
    for (int nc = 0; nc < 2; ++nc) {
        gemm_bt<M_GELU, 0><<<dim3(8, 256), 256, 0, stream>>>(
            h2, 512, fc1T + (size_t)nc * 1024 * 512, 512,
            fc1_b + nc * 1024, gbuf, nullptr, 512, 1024);
        gemm_bt<M_FINAL, 0><<<dim3(4, 256), 256, 0, stream>>>(
            gbuf, 1024, fc2T + nc * 1024, 2048,
            (nc == 0 ? fc2_b : nullptr), out, nullptr, 1024, 0);
    }
}

// Round 10
// 498.938 us; speedup vs baseline: 1.0224x; 1.0224x over previous
//
#include <hip/hip_runtime.h>
#include <cstddef>
#include <cstdint>

// ---------------------------------------------------------------------------
// Swin block. f32 in/out; internal bf16 MFMA. B=8 H=W=64 DIM=512 NH=16 HD=32.
// GEMM: MTx128 tile (MT=128 default, 64 for M_FINAL), BK=64, 2-barrier loop,
// LINEAR LDS staged via global_load_lds width=16 (m97 structure, verified
// R4: 830 TF QKV). R8 ring (645 TF) and R9 N-split (double out-RMW, +10us)
// both LOST to this — keep it.
// MT=64 for FINAL: grid (4,256)=1024 blocks = 4 blocks/CU (M-split FINAL at
// MT=128 was 512 blocks = 2/CU, half the TLP that hides staging latency).
// One RMW pass over out (unlike R9's N-split double-RMW).
// Bank-conflict fix (rule #21): LDS dest linear, global SOURCE chunk XOR-
// swizzled (c ^= row&7), same XOR on ds_read side -> conflicts = 0.
// launch_bounds(256,4): VGPR=60. (256,5) strangles VGPR->48 (R2: 803us).
// T1: bijective XCD swizzle (verified R4: QKV FETCH 135->28MB).
// M_GELU: branch-free A&S erf (verified R3).
// ws: [0,6.3M) bf16 weights | q[8,40) k[40,72) v[72,104) MB
//     h2 overlays q after proj; gbuf (16384x2048 bf16) overlays k+v.
// xw (LN1+shift, bf16 32MB) lives in d_out (dead until proj overwrites it).
// ---------------------------------------------------------------------------

typedef unsigned short u16;
typedef __attribute__((ext_vector_type(8))) short short8;
typedef __attribute__((ext_vector_type(4))) float floatx4;

__device__ __forceinline__ float bf2f(u16 u) {
    union { float f; unsigned i; } w; w.i = ((unsigned)u) << 16; return w.f;
}
__device__ __forceinline__ u16 f2bf(float f) {
    union { float f; unsigned i; } w; w.f = f;
    unsigned r = w.i + 0x7FFF + ((w.i >> 16) & 1);   // RNE
    return (u16)(r >> 16);
}

__device__ __forceinline__ void gload_lds16(const u16* g, u16* l) {
    __builtin_amdgcn_global_load_lds(
        (const __attribute__((address_space(1))) void*)g,
        (__attribute__((address_space(3))) void*)l, 16, 0, 0);
}

// branch-free erf, A&S 7.1.26, |err| < 1.5e-7 (invisible at bf16 precision)
__device__ __forceinline__ float erf_fast(float x) {
    float ax = fabsf(x);
    float t = 1.0f / (1.0f + 0.3275911f * ax);
    float poly = ((((1.061405429f * t - 1.453152027f) * t + 1.421413741f) * t
                   - 0.284496736f) * t + 0.254829592f) * t;
    float er = 1.0f - poly * __expf(-ax * ax);
    return copysignf(er, x);
}

__device__ __forceinline__ int win_to_img_row(int t) {
    int win = t >> 6, n = t & 63;
    int b = win >> 6, wr = (win >> 3) & 7, wc = win & 7;
    int h = ((wr << 3) + (n >> 3) + 4) & 63;
    int w = ((wc << 3) + (n & 7) + 4) & 63;
    return (b << 12) + (h << 6) + w;
}

// ---------------------------------------------------------------------------
// Fused LayerNorm: one wave per 512-dim row, single pass.
// ---------------------------------------------------------------------------
__global__ __launch_bounds__(256) void ln_fused(
    const float* __restrict__ x, const float* __restrict__ g,
    const float* __restrict__ b, u16* __restrict__ out, int gather)
{
    int wave = threadIdx.x >> 6, lane = threadIdx.x & 63;
    int t = blockIdx.x * 4 + wave;
    int src = gather ? win_to_img_row(t) : t;
    const float* xr = x + (size_t)src * 512 + lane * 8;
    float4 a = *(const float4*)xr;
    float4 c = *(const float4*)(xr + 4);
    float s = a.x + a.y + a.z + a.w + c.x + c.y + c.z + c.w;
    float s2 = a.x*a.x + a.y*a.y + a.z*a.z + a.w*a.w
             + c.x*c.x + c.y*c.y + c.z*c.z + c.w*c.w;
#pragma unroll
    for (int off = 32; off; off >>= 1) { s += __shfl_down(s, off); s2 += __shfl_down(s2, off); }
    s = __shfl(s, 0); s2 = __shfl(s2, 0);
    float mu = s * (1.f / 512.f);
    float var = s2 * (1.f / 512.f) - mu * mu;
    float rs = rsqrtf(var + 1e-5f);
    int col = lane * 8;
    float4 g0 = *(const float4*)(g + col), g1 = *(const float4*)(g + col + 4);
    float4 b0 = *(const float4*)(b + col), b1 = *(const float4*)(b + col + 4);
    u16 r[8];
    r[0] = f2bf((a.x - mu) * rs * g0.x + b0.x);
    r[1] = f2bf((a.y - mu) * rs * g0.y + b0.y);
    r[2] = f2bf((a.z - mu) * rs * g0.z + b0.z);
    r[3] = f2bf((a.w - mu) * rs * g0.w + b0.w);
    r[4] = f2bf((c.x - mu) * rs * g1.x + b1.x);
    r[5] = f2bf((c.y - mu) * rs * g1.y + b1.y);
    r[6] = f2bf((c.z - mu) * rs * g1.z + b1.z);
    r[7] = f2bf((c.w - mu) * rs * g1.w + b1.w);
    *(uint4*)(out + (size_t)t * 512 + col) = *(const uint4*)r;
}

// ---------------------------------------------------------------------------
// All four weight transposes in ONE launch.
// ---------------------------------------------------------------------------
__global__ __launch_bounds__(256) void transpose_all(
    const float* __restrict__ qkv_w, const float* __restrict__ proj_w,
    const float* __restrict__ fc1_w, const float* __restrict__ fc2_w,
    u16* __restrict__ qkvT, u16* __restrict__ projT,
    u16* __restrict__ fc1T, u16* __restrict__ fc2T)
{
    int bid = blockIdx.x;
    const float* W; u16* WT; int K, N, base;
    if (bid < 384)       { W = qkv_w;  WT = qkvT;  K = 512;  N = 1536; base = 0; }
    else if (bid < 512)  { W = proj_w; WT = projT; K = 512;  N = 512;  base = 384; }
    else if (bid < 1024) { W = fc1_w;  WT = fc1T;  K = 512;  N = 2048; base = 512; }
    else                 { W = fc2_w;  WT = fc2T;  K = 2048; N = 512;  base = 1024; }
    int f = (bid - base) * 256 + threadIdx.x;
    int n = f % N, kc = f / N;
    if (kc >= (K >> 3)) return;
    int k0 = kc << 3;
    u16 r[8];
#pragma unroll
    for (int j = 0; j < 8; ++j) r[j] = f2bf(W[(size_t)(k0 + j) * N + n]);
    *(uint4*)(WT + (size_t)n * K + k0) = *(const uint4*)r;
}

// ---------------------------------------------------------------------------
// MFMA GEMM: MTx128 tile (MT in {128,64}), BK=64, linear LDS, staged with
// global_load_lds width=16. 4 waves, 2Mx2N: per-wave tile (MT/2)x64 =
// MSUB x 4 of 16x16. Staging f-index: row=f>>3, chunk c=f&7, LDS byte=f*16;
// source chunk swizzle cs = c ^ (row&7); ds_read applies the same XOR.
// Grid: T1 bijective XCD swizzle. ASRC: 0 plain A[lda] | 3 qkv-slice gather.
// ldo: output row stride for M_GELU.
// ---------------------------------------------------------------------------
enum { M_QKV = 0, M_PROJ = 1, M_GELU = 2, M_FINAL = 3 };

template <int MODE, int ASRC, int MT = 128>
__global__ __launch_bounds__(256, 4) void gemm_bt(
    const u16* __restrict__ A, int lda,
    const u16* __restrict__ BT, int ldb,
    const float* __restrict__ bias,
    void* __restrict__ outp, const float* __restrict__ auxf, int K, int ldo)
{
    constexpr int MSUB = MT / 32;            // 16-row subtiles per wave (M)
    __shared__ __align__(16) u16 As[MT * 64];
    __shared__ __align__(16) u16 Bs[128 * 64];

    int tid = threadIdx.x;
    // ---- T1: bijective XCD-aware block swizzle (8 XCDs) ----
    int nwg = gridDim.x * gridDim.y;
    int bid = blockIdx.y * gridDim.x + blockIdx.x;
    int q8 = nwg >> 3, r8 = nwg & 7;
    int xcd = bid & 7, pos = bid >> 3;
    int swz = (xcd < r8 ? xcd * (q8 + 1)
                        : r8 * (q8 + 1) + (xcd - r8) * q8) + pos;
    int bx = swz % gridDim.x, by = swz / gridDim.x;
    int bm = by * MT, bn = bx * 128;

    int wave = tid >> 6, lane = tid & 63;
    int quad = lane >> 4, lr = lane & 15;
    int wm = (wave >> 1) * (MT / 2), wn = (wave & 1) * 64;

    floatx4 acc[MSUB][4] = {};

    for (int k0 = 0; k0 < K; k0 += 64) {
#pragma unroll
        for (int l = 0; l < 4; ++l) {          // B: 1024 chunks
            int f = (l << 8) + tid;
            int row = f >> 3, c = f & 7;
            int kk = k0 + ((c ^ (row & 7)) << 3);
            gload_lds16(BT + (size_t)(bn + row) * ldb + kk, Bs + f * 8);
        }
#pragma unroll
        for (int l = 0; l < MT / 32; ++l) {    // A: MT*8 chunks
            int f = (l << 8) + tid;
            int row = f >> 3, c = f & 7;
            int kk = k0 + ((c ^ (row & 7)) << 3);
            if constexpr (ASRC == 0) {
                gload_lds16(A + (size_t)(bm + row) * lda + kk, As + f * 8);
            } else {  // qkv-slice gather: [ (win*16+head)*2048 + tok*32 + d ]
                int m = bm + row;
                gload_lds16(A + (size_t)(((m >> 6) << 4) + (kk >> 5)) * 2048
                              + (m & 63) * 32 + (kk & 31), As + f * 8);
            }
        }
        __syncthreads();   // drains vmcnt(0): loads have landed in LDS
#pragma unroll
        for (int step = 0; step < 2; ++step) {
            short8 af[MSUB], bv[4];
            int kc = step * 4 + quad;
#pragma unroll
            for (int t = 0; t < MSUB; ++t) {
                int ra = wm + t * 16 + lr;
                af[t] = *(const short8*)(As + ra * 64 + ((kc ^ (ra & 7)) << 3));
            }
#pragma unroll
            for (int t = 0; t < 4; ++t) {
                int rb = wn + t * 16 + lr;
                bv[t] = *(const short8*)(Bs + rb * 64 + ((kc ^ (rb & 7)) << 3));
            }
#pragma unroll
            for (int mt = 0; mt < MSUB; ++mt)
#pragma unroll
                for (int nt = 0; nt < 4; ++nt)
                    acc[mt][nt] = __builtin_amdgcn_mfma_f32_16x16x32_bf16(
                        af[mt], bv[nt], acc[mt][nt], 0, 0, 0);
        }
        __syncthreads();
    }

#pragma unroll
    for (int mt = 0; mt < MSUB; ++mt) {
#pragma unroll
        for (int nt = 0; nt < 4; ++nt) {
            int m0 = bm + wm + mt * 16 + quad * 4;
            int n = bn + wn + nt * 16 + lr;
#pragma unroll
            for (int i = 0; i < 4; ++i) {
                int m = m0 + i;
                float v = acc[mt][nt][i];
                if constexpr (MODE == M_QKV) {
                    v += bias[n];
                    int sel = n >> 9, head = (n >> 5) & 15, d = n & 31;
                    int wh = (m >> 6) * 16 + head, tok = m & 63;
                    ((u16*)outp)[(size_t)sel * 16777216 + (size_t)wh * 2048 + tok * 32 + d] = f2bf(v);
                } else if constexpr (MODE == M_PROJ) {
                    size_t idx = (size_t)win_to_img_row(m) * 512 + n;
                    ((float*)outp)[idx] = v + bias[n] + auxf[idx];
                } else if constexpr (MODE == M_GELU) {
                    v += bias[n];
                    float gel = 0.5f * v * (1.0f + erf_fast(v * 0.70710678118654752f));
                    ((u16*)outp)[(size_t)m * ldo + n] = f2bf(gel);
                } else { // M_FINAL: outp = xres f32, read-modify-write
                    size_t idx = (size_t)m * 512 + n;
                    float* o = (float*)outp;
                    o[idx] = o[idx] + v + bias[n];
                }
            }
        }
    }
}

// ---------------------------------------------------------------------------
// MFMA attention (unchanged): block = 4 waves = 4 windows x 1 head.
// No T1 here: each block reads private q/k/v rows (zero inter-block reuse).
// ---------------------------------------------------------------------------
__global__ __launch_bounds__(256) void attn_mfma(
    const u16* __restrict__ qkv, const float* __restrict__ table,
    u16* __restrict__ outp)
{
    __shared__ __align__(8) u16 PT[4][64 * 76];
    __shared__ float blds[225];

    int w = threadIdx.x >> 6, lane = threadIdx.x & 63;
    int head = blockIdx.x & 15, win = ((blockIdx.x >> 4) << 2) + w;
    int wh = (win << 4) + head;
    int quad = lane >> 4, lr = lane & 15;
    const u16* qb = qkv + (size_t)wh * 2048;
    const u16* kb = qb + 16777216;
    const u16* vb = qb + 33554432;
    u16* PTw = PT[w];

    for (int i = threadIdx.x; i < 225; i += 256) blds[i] = table[i * 16 + head];
    __syncthreads();

    short8 qf[4], kf[4];
#pragma unroll
    for (int t = 0; t < 4; ++t) {
        qf[t] = *(const short8*)(qb + (t * 16 + lr) * 32 + quad * 8);
        kf[t] = *(const short8*)(kb + (t * 16 + lr) * 32 + quad * 8);
    }
    floatx4 s[4][4] = {};
#pragma unroll
    for (int mi = 0; mi < 4; ++mi)
#pragma unroll
        for (int ni = 0; ni < 4; ++ni)
            s[mi][ni] = __builtin_amdgcn_mfma_f32_16x16x32_bf16(qf[mi], kf[ni], s[mi][ni], 0, 0, 0);

    short8 vf[2][2];
#pragma unroll
    for (int ks = 0; ks < 2; ++ks)
#pragma unroll
        for (int nd = 0; nd < 2; ++nd)
#pragma unroll
            for (int j = 0; j < 8; ++j)
                vf[ks][nd][j] = (short)vb[(ks * 32 + quad * 8 + j) * 32 + nd * 16 + lr];

    int wr = (win >> 3) & 7, wc = win & 7;
    int rj[4], cj[4], regj[4];
#pragma unroll
    for (int ni = 0; ni < 4; ++ni) {
        int kj = ni * 16 + lr;
        rj[ni] = kj >> 3; cj[ni] = kj & 7;
        int hJ = wr * 8 + rj[ni], wJ = wc * 8 + cj[ni];
        regj[ni] = (hJ < 56 ? 0 : (hJ < 60 ? 1 : 2)) * 3 + (wJ < 56 ? 0 : (wJ < 60 ? 1 : 2));
    }
    float rm[4][4], linv[4][4];
#pragma unroll
    for (int mi = 0; mi < 4; ++mi) {
#pragma unroll
        for (int i = 0; i < 4; ++i) {
            int qi = mi * 16 + quad * 4 + i;
            int ri = qi >> 3, ci = qi & 7;
            int hI = wr * 8 + ri, wI = wc * 8 + ci;
            int regi = (hI < 56 ? 0 : (hI < 60 ? 1 : 2)) * 3 + (wI < 56 ? 0 : (wI < 60 ? 1 : 2));
            float mx = -1e30f;
#pragma unroll
            for (int ni = 0; ni < 4; ++ni) {
                float v = s[mi][ni][i] * 0.17677669529663687f
                        + blds[(ri - rj[ni] + 7) * 15 + (ci - cj[ni] + 7)];
                if (regj[ni] != regi) v -= 100.f;
                s[mi][ni][i] = v;
                mx = fmaxf(mx, v);
            }
            rm[mi][i] = mx;
        }
    }
#pragma unroll
    for (int mi = 0; mi < 4; ++mi)
#pragma unroll
        for (int i = 0; i < 4; ++i) {
            float mx = rm[mi][i];
#pragma unroll
            for (int msk = 1; msk < 16; msk <<= 1) mx = fmaxf(mx, __shfl_xor(mx, msk));
            float sum = 0.f;
#pragma unroll
            for (int ni = 0; ni < 4; ++ni) {
                float e = __expf(s[mi][ni][i] - mx);
                s[mi][ni][i] = e;
                sum += e;
            }
#pragma unroll
            for (int msk = 1; msk < 16; msk <<= 1) sum += __shfl_xor(sum, msk);
            linv[mi][i] = 1.f / sum;
        }

#pragma unroll
    for (int mi = 0; mi < 4; ++mi)
#pragma unroll
        for (int ni = 0; ni < 4; ++ni) {
            unsigned lo = (unsigned)f2bf(s[mi][ni][0]) | ((unsigned)f2bf(s[mi][ni][1]) << 16);
            unsigned hi = (unsigned)f2bf(s[mi][ni][2]) | ((unsigned)f2bf(s[mi][ni][3]) << 16);
            uint2 pk = make_uint2(lo, hi);
            *(uint2*)(PTw + (ni * 16 + lr) * 76 + mi * 16 + quad * 4) = pk;
        }
    __syncthreads();

    floatx4 o[4][2] = {};
#pragma unroll
    for (int mi = 0; mi < 4; ++mi) {
#pragma unroll
        for (int ks = 0; ks < 2; ++ks) {
            short8 pa;
#pragma unroll
            for (int j = 0; j < 8; ++j)
                pa[j] = (short)PTw[(ks * 32 + quad * 8 + j) * 76 + mi * 16 + lr];
#pragma unroll
            for (int nd = 0; nd < 2; ++nd)
                o[mi][nd] = __builtin_amdgcn_mfma_f32_16x16x32_bf16(pa, vf[ks][nd], o[mi][nd], 0, 0, 0);
        }
    }
    u16* ob = outp + (size_t)wh * 2048;
#pragma unroll
    for (int mi = 0; mi < 4; ++mi)
#pragma unroll
        for (int nd = 0; nd < 2; ++nd)
#pragma unroll
            for (int i = 0; i < 4; ++i) {
                int qi = mi * 16 + quad * 4 + i;
                ob[qi * 32 + nd * 16 + lr] = f2bf(o[mi][nd][i] * linv[mi][i]);
            }
}

// ---------------------------------------------------------------------------
extern "C" void kernel_launch(void* const* d_in, const int* in_sizes, int n_in,
                              void* d_out, int out_size, void* d_ws, size_t ws_size,
                              hipStream_t stream)
{
    (void)in_sizes; (void)n_in; (void)out_size; (void)ws_size;
    const float* x      = (const float*)d_in[0];
    const float* n1g    = (const float*)d_in[2];
    const float* n1b    = (const float*)d_in[3];
    const float* qkv_w  = (const float*)d_in[4];
    const float* qkv_b  = (const float*)d_in[5];
    const float* table  = (const float*)d_in[6];
    const float* proj_w = (const float*)d_in[7];
    const float* proj_b = (const float*)d_in[8];
    const float* n2g    = (const float*)d_in[9];
    const float* n2b    = (const float*)d_in[10];
    const float* fc1_w  = (const float*)d_in[11];
    const float* fc1_b  = (const float*)d_in[12];
    const float* fc2_w  = (const float*)d_in[13];
    const float* fc2_b  = (const float*)d_in[14];
    float* out = (float*)d_out;
    char* ws = (char*)d_ws;

    u16* qkvT  = (u16*)ws;                  // 786432
    u16* projT = qkvT + 786432;             // 262144
    u16* fc1T  = projT + 262144;            // 1048576
    u16* fc2T  = fc1T + 1048576;            // 1048576 (ends 6,291,456 B)
    u16* q    = (u16*)(ws + 8388608);       // q,k,v 3x32MB (ends 104 MB)
    u16* h2   = q;                          // overlays q after proj
    u16* gbuf = q + 16777216;               // 64 MB over k+v (dead post-attn)
    u16* xw   = (u16*)d_out;                // LN1+shift bf16, dead before proj

    transpose_all<<<1536, 256, 0, stream>>>(
        qkv_w, proj_w, fc1_w, fc2_w, qkvT, projT, fc1T, fc2T);

    // LN1 + shift/window gather -> xw (in d_out)
    ln_fused<<<8192, 256, 0, stream>>>(x, n1g, n1b, xw, 1);
    // QKV from xw (M=32768, N=1536, K=512)
    gemm_bt<M_QKV, 0><<<dim3(12, 256), 256, 0, stream>>>(
        xw, 512, qkvT, 512, qkv_b, q, nullptr, 512, 0);
    attn_mfma<<<2048, 256, 0, stream>>>(q, table, q);
    // proj + reverse-shift scatter + residual -> d_out (overwrites xw fully)
    gemm_bt<M_PROJ, 3><<<dim3(4, 256), 256, 0, stream>>>(
        q, 0, projT, 512, proj_b, out, x, 512, 0);
    // LN2 -> h2 (full 32768 rows)
    ln_fused<<<8192, 256, 0, stream>>>(out, n2g, n2b, h2, 0);
    // MLP, M-split (one RMW pass over out). FINAL uses MT=64 tiles:
    // grid (4,256) = 1024 blocks = 4 blocks/CU (MT=128 was 512 = 2/CU).
    for (int mc = 0; mc < 2; ++mc) {
        gemm_bt<M_GELU, 0><<<dim3(16, 128), 256, 0, stream>>>(
            h2 + (size_t)mc * 16384 * 512, 512, fc1T, 512, fc1_b,
            gbuf, nullptr, 512, 2048);
        gemm_bt<M_FINAL, 0, 64><<<dim3(4, 256), 256, 0, stream>>>(
            gbuf, 2048, fc2T, 2048, fc2_b,
            out + (size_t)mc * 16384 * 512, nullptr, 2048, 0);
    }
}